// Round 5
// baseline (32841.522 us; speedup 1.0000x reference)
//
#include <hip/hip_runtime.h>
#include <math.h>

// Problem constants
#define BB  128      // batch
#define NN  400      // spatial locations
#define EE  512      // encoder size
#define SHD 256      // structural hidden
#define HH  512      // cell hidden
#define AA  256      // attention size
#define EMBD 256     // embedding size
#define VV  1000     // vocab
#define TT  256      // timesteps
#define TH3 (3*HH)          // 1536
#define BNROWS (BB*NN)      // 51200
#define PRED_STRIDE (BB*VV) // 128000
#define NPRED ((size_t)TT*BB*VV)

__device__ __forceinline__ float tanh_fast(float x){
    // tanh(x) = 1 - 2/(exp(2x)+1); exact at +/-inf saturation
    float e = __expf(2.f*x);
    return 1.f - 2.f*__builtin_amdgcn_rcpf(e + 1.f);
}

// ---------------- prologue kernels (one-time) ----------------

__global__ void k_zero(float* __restrict__ hbuf0, float* __restrict__ loss_acc){
    int i = blockIdx.x*blockDim.x + threadIdx.x;
    if (i < BB*HH) hbuf0[i] = 0.f;
    if (i == 0) loss_acc[0] = 0.f;
}

// fpT[b][a][n] = features[b,n,:] @ Wf[:,a] + bf[a]   TRANSPOSED store so the
// per-step score phase reads coalesced along n.
__global__ __launch_bounds__(256) void k_featproj(
    const float* __restrict__ feats, const float* __restrict__ Wf,
    const float* __restrict__ bf, float* __restrict__ fpT)
{
    __shared__ float As[32][65]; // [k][m]
    __shared__ float Bs[32][65]; // [k][n]
    int row0 = blockIdx.x*64, col0 = blockIdx.y*64;
    int tx = threadIdx.x & 15, ty = threadIdx.x >> 4;
    float acc[4][4] = {};
    for (int k0 = 0; k0 < EE; k0 += 32){
        for (int idx = threadIdx.x; idx < 64*32; idx += 256){
            int r = idx >> 5, kk = idx & 31;
            As[kk][r] = feats[(size_t)(row0 + r)*EE + k0 + kk];
        }
        for (int idx = threadIdx.x; idx < 32*64; idx += 256){
            int kk = idx >> 6, c = idx & 63;
            Bs[kk][c] = Wf[(size_t)(k0 + kk)*AA + col0 + c];
        }
        __syncthreads();
        #pragma unroll
        for (int kk = 0; kk < 32; ++kk){
            float a0 = As[kk][ty*4+0], a1 = As[kk][ty*4+1], a2 = As[kk][ty*4+2], a3 = As[kk][ty*4+3];
            float b0 = Bs[kk][tx*4+0], b1 = Bs[kk][tx*4+1], b2 = Bs[kk][tx*4+2], b3 = Bs[kk][tx*4+3];
            acc[0][0] += a0*b0; acc[0][1] += a0*b1; acc[0][2] += a0*b2; acc[0][3] += a0*b3;
            acc[1][0] += a1*b0; acc[1][1] += a1*b1; acc[1][2] += a1*b2; acc[1][3] += a1*b3;
            acc[2][0] += a2*b0; acc[2][1] += a2*b1; acc[2][2] += a2*b2; acc[2][3] += a2*b3;
            acc[3][0] += a3*b0; acc[3][1] += a3*b1; acc[3][2] += a3*b2; acc[3][3] += a3*b3;
        }
        __syncthreads();
    }
    #pragma unroll
    for (int i = 0; i < 4; ++i){
        int row = row0 + ty*4 + i;          // global (b,n) row
        int b = row/NN, n = row - b*NN;
        #pragma unroll
        for (int j = 0; j < 4; ++j){
            int col = col0 + tx*4 + j;
            fpT[((size_t)b*AA + col)*NN + n] = acc[i][j] + bf[col];
        }
    }
}

// transpose the EMB part of W_ih:  wT[m, r] = W_ih[r, EE+m]
__global__ void k_wembT(const float* __restrict__ Wih, float* __restrict__ wT){
    int i = blockIdx.x*blockDim.x + threadIdx.x;
    if (i >= EMBD*TH3) return;
    int m = i / TH3, r = i - m*TH3;
    wT[i] = Wih[(size_t)r*(EE+EMBD) + EE + m];
}

// transpose W_fc:  WfcT[v][h] = W_fc[h*VV + v]  (so logits stream float4 rows)
__global__ void k_wfcT(const float* __restrict__ Wfc, float* __restrict__ WfcT){
    int i = blockIdx.x*blockDim.x + threadIdx.x;
    if (i >= VV*HH) return;
    int v = i / HH, h = i - v*HH;
    WfcT[i] = Wfc[(size_t)h*VV + v];
}

// emb_proj[v, r] = emb[v,:] @ W_ih_emb^T + b_ih[r]   (1000x256 @ 256x1536)
__global__ __launch_bounds__(256) void k_embproj(
    const float* __restrict__ emb, const float* __restrict__ wT,
    const float* __restrict__ bih, float* __restrict__ ep)
{
    __shared__ float el[16][257];
    int vt = blockIdx.x, rc = blockIdx.y;
    for (int idx = threadIdx.x; idx < 16*EMBD; idx += 256){
        int v = idx >> 8, m = idx & 255;
        int gv = vt*16 + v;
        el[v][m] = (gv < VV) ? emb[(size_t)gv*EMBD + m] : 0.f;
    }
    __syncthreads();
    int r = rc*256 + threadIdx.x;
    float acc[16] = {};
    for (int m = 0; m < EMBD; ++m){
        float w = wT[(size_t)m*TH3 + r];
        #pragma unroll
        for (int v = 0; v < 16; ++v) acc[v] += el[v][m]*w;
    }
    float bb_ = bih[r];
    #pragma unroll
    for (int v = 0; v < 16; ++v){
        int gv = vt*16 + v;
        if (gv < VV) ep[(size_t)gv*TH3 + r] = acc[v] + bb_;
    }
}

// sp2[b,a] = sh[0,b,:] @ Ws[:,a] + bs[a] + bc[a]   (bc folded in)
__global__ void k_structproj(const float* __restrict__ sh, const float* __restrict__ Ws,
                             const float* __restrict__ bs, const float* __restrict__ bc,
                             float* __restrict__ sp){
    __shared__ float sl[SHD];
    int b = blockIdx.x;
    for (int i = threadIdx.x; i < SHD; i += 256) sl[i] = sh[(size_t)b*SHD + i];
    __syncthreads();
    int a = threadIdx.x;
    float acc = 0.f;
    for (int s = 0; s < SHD; ++s) acc += sl[s]*Ws[(size_t)s*AA + a];
    sp[(size_t)b*AA + a] = acc + bs[a] + bc[a];
}

// ---------------- shared device bodies ----------------

// logits for step tpred: preds[tpred] = h(tpred+1) @ WfcT^T + b_fc (512 threads)
// float4 streaming of WfcT rows; NONTEMPORAL stores (preds is 524MB write-once;
// keep it out of L3 so the hot ~170MB fpT+feats stay cache-resident).
__device__ __forceinline__ void logits_body(int tpred, int bt, int vt,
    const float* __restrict__ hsrc, const float* __restrict__ WfcT,
    const float* __restrict__ bfc, float* __restrict__ preds, float* hl)
{
    for (int idx = threadIdx.x; idx < 8*HH; idx += 512){
        int bl = idx >> 9;
        hl[idx] = hsrc[(size_t)(bt*8+bl)*HH + (idx & 511)];
    }
    __syncthreads();
    for (int o = threadIdx.x; o < 1000; o += 512){
        int bl = o / 125, vl = o - bl*125;
        int v = vt*125 + vl;
        const float4* wrow = (const float4*)(WfcT + (size_t)v*HH);
        const float4* hrow = (const float4*)(hl + bl*HH);
        float acc = 0.f;
        #pragma unroll 8
        for (int h4 = 0; h4 < HH/4; ++h4){
            float4 w = wrow[h4], hh = hrow[h4];
            acc += w.x*hh.x + w.y*hh.y + w.z*hh.z + w.w*hh.w;
        }
        __builtin_nontemporal_store(acc + bfc[v],
            &preds[(size_t)tpred*PRED_STRIDE + (size_t)(bt*8+bl)*VV + v]);
    }
}

// loss for step tpred over rows [lb*16, lb*16+16); any blockDim multiple of 64.
// Precise expf/logf: this path is cheap (~128K transcendentals/step) and its
// result feeds the scalar loss output directly.
__device__ __forceinline__ void loss_body(int tpred, int lb,
    const float* __restrict__ preds, const int* __restrict__ tgt, float* loss_acc)
{
    int w = threadIdx.x >> 6, lane = threadIdx.x & 63;
    int nw = blockDim.x >> 6;
    float contrib = 0.f;
    for (int ri = w; ri < 16; ri += nw){
        int row = lb*16 + ri;
        const float* p = preds + (size_t)tpred*PRED_STRIDE + (size_t)row*VV;
        float m = -1e30f;
        for (int i = lane; i < VV; i += 64) m = fmaxf(m, __builtin_nontemporal_load(p + i));
        #pragma unroll
        for (int off = 32; off; off >>= 1) m = fmaxf(m, __shfl_xor(m, off));
        float s = 0.f;
        for (int i = lane; i < VV; i += 64) s += expf(__builtin_nontemporal_load(p + i) - m);
        #pragma unroll
        for (int off = 32; off; off >>= 1) s += __shfl_xor(s, off);
        if (lane == 0) contrib += m + logf(s) - p[tgt[(size_t)row*TT + tpred]];
    }
    if (lane == 0) atomicAdd(loss_acc, contrib);
}

// ---------------- per-step kernel 1: attention (+ logits(t-1)) ----------------
// blocks 0..511 : (b, quarter-of-N) attention partials — streaming, no shuffles
// blocks 512..639: logits for step t-1 (skipped at t==0)
__global__ __launch_bounds__(512) void k_attn(int t,
    const float* __restrict__ fpT, const float* __restrict__ feats,
    const float* __restrict__ sp2, const float* __restrict__ vatt,
    const float* __restrict__ qpart, const float* __restrict__ hin,
    const float* __restrict__ WfcT, const float* __restrict__ bfc,
    float* __restrict__ pctx, float* __restrict__ psum, float* __restrict__ preds)
{
    __shared__ __align__(16) float smem[4160];
    if (blockIdx.x >= 512){
        if (t == 0) return;
        int lb = blockIdx.x - 512;
        logits_body(t-1, lb >> 3, lb & 7, hin, WfcT, bfc, preds, smem);
        return;
    }
    int b = blockIdx.x >> 2, qtr = blockIdx.x & 3;
    const int nbase = qtr*100;
    float* qs = smem;            // [256]
    float* vs = smem + 256;      // [256]
    float* sA = smem + 512;      // [4][128]
    float* al = smem + 1024;     // [128]
    // q(t) = struct_proj(+bs+bc) + sum of 32 partial h@Wc slices from prev k_gru
    if (threadIdx.x < AA){
        int a = threadIdx.x;
        float val = sp2[(size_t)b*AA + a];
        if (t > 0){
            #pragma unroll 4
            for (int jt = 0; jt < 32; ++jt) val += qpart[((size_t)jt*BB + b)*AA + a];
        }
        qs[a] = val;
        vs[a] = vatt[a];
    }
    __syncthreads();
    // Phase A: scores. thread -> (n_local = tid&127, a_quarter = tid>>7).
    // Loads coalesced along n; q/v broadcast from LDS. No cross-lane ops.
    int nl = threadIdx.x & 127, ah = threadIdx.x >> 7;
    float sacc = 0.f;
    if (nl < 100){
        const float* fr = fpT + ((size_t)b*AA + ah*64)*NN + nbase + nl;
        #pragma unroll 4
        for (int i = 0; i < 64; ++i)
            sacc += vs[ah*64 + i]*tanh_fast(fr[(size_t)i*NN] + qs[ah*64 + i]);
    }
    sA[ah*128 + nl] = sacc;
    __syncthreads();
    if (threadIdx.x < 128){
        float e = 0.f;
        if (threadIdx.x < 100)
            e = __expf(sA[threadIdx.x] + sA[128 + threadIdx.x] +
                       sA[256 + threadIdx.x] + sA[384 + threadIdx.x]);
        al[threadIdx.x] = e;   // |s| <= sum|v| ~ 10: exp safe in f32 without max-sub
    }
    __syncthreads();
    if (threadIdx.x < 64){
        float e = al[threadIdx.x] + al[threadIdx.x + 64];
        #pragma unroll
        for (int off = 32; off; off >>= 1) e += __shfl_xor(e, off);
        if (threadIdx.x == 0) psum[b*4 + qtr] = e;
    }
    // Phase B: unnormalized context. thread -> e; coalesced feats stream.
    {
        int e = threadIdx.x;
        float c0=0.f, c1=0.f, c2=0.f, c3=0.f;
        const float* fb = feats + ((size_t)b*NN + nbase)*EE + e;
        for (int n = 0; n < 100; n += 4){
            c0 += al[n+0]*fb[(size_t)(n+0)*EE];
            c1 += al[n+1]*fb[(size_t)(n+1)*EE];
            c2 += al[n+2]*fb[(size_t)(n+2)*EE];
            c3 += al[n+3]*fb[(size_t)(n+3)*EE];
        }
        pctx[((size_t)b*4 + qtr)*EE + e] = (c0+c1)+(c2+c3);
    }
}

// ---------------- per-step kernel 2: GRU (+ q-partials, + loss(t-1)) ----------------
// blocks 0..255 : (b_tile=16) x (j_tile=16 of H), 512 threads, 2-way e-split.
// LDS = 79.3KB -> 2 blocks/CU (one scheduling wave for 264 blocks).
// blocks 256..263: loss for step t-1 (skipped at t==0)
__global__ __launch_bounds__(512) void k_gru(int t,
    const float* __restrict__ pctx, const float* __restrict__ psum,
    const float* __restrict__ hin, float* __restrict__ hout,
    const float* __restrict__ Wih, const float* __restrict__ Whh,
    const float* __restrict__ bhh, const float* __restrict__ embp,
    const int* __restrict__ tgt, const float* __restrict__ Wc,
    float* __restrict__ qpart, const float* __restrict__ preds,
    float* __restrict__ loss_acc)
{
    if (blockIdx.x >= 256){
        if (t > 0) loss_body(t-1, (int)blockIdx.x - 256, preds, tgt, loss_acc);
        return;
    }
    __shared__ __align__(16) float stC[16][516];   // pad 516: dot-phase lane stride
    __shared__ __align__(16) float stH[16][516];   // -> 2-way bank alias (free)
    __shared__ float pGI[2][16][16][3];
    __shared__ float pGH[2][16][16][3];
    __shared__ float hn_l[16][16];
    int bt = blockIdx.x >> 5, jt = blockIdx.x & 31;
    int bg = bt*16, jbase = jt*16;
    int p = threadIdx.x & 255, role = threadIdx.x >> 8;
    int b = p & 15, j = p >> 4, r0 = jbase + j;
    // stage h and normalized context (combine 4 quarter-partials)
    for (int idx = threadIdx.x; idx < 16*HH; idx += 512){
        int bb_ = idx >> 9, e = idx & 511;
        stH[bb_][e] = hin[(size_t)(bg+bb_)*HH + e];
    }
    for (int idx = threadIdx.x; idx < 16*EE; idx += 512){
        int bb_ = idx >> 9, e = idx & 511;
        const float* ps4 = psum + (size_t)(bg+bb_)*4;
        float iv = 1.f/(ps4[0]+ps4[1]+ps4[2]+ps4[3]);
        const float* pc = pctx + (size_t)(bg+bb_)*4*EE + e;
        stC[bb_][e] = (pc[0] + pc[EE] + pc[2*(size_t)EE] + pc[3*(size_t)EE]) * iv;
    }
    __syncthreads();
    // both dot phases fused: 6 chains, float4 weight streams (VMEM issue /4)
    {
        const float4* w0 = (const float4*)(Wih + (size_t)r0*(EE+EMBD));
        const float4* w1 = (const float4*)(Wih + (size_t)(r0+512)*(EE+EMBD));
        const float4* w2 = (const float4*)(Wih + (size_t)(r0+1024)*(EE+EMBD));
        const float4* u0 = (const float4*)(Whh + (size_t)r0*HH);
        const float4* u1 = (const float4*)(Whh + (size_t)(r0+512)*HH);
        const float4* u2 = (const float4*)(Whh + (size_t)(r0+1024)*HH);
        float ar=0,az=0,an=0, br=0,bz=0,bn=0;
        const float4* crow = (const float4*)&stC[b][0];
        const float4* hrow = (const float4*)&stH[b][0];
        int e40 = role*64;
        #pragma unroll 4
        for (int e4 = e40; e4 < e40 + 64; ++e4){
            float4 c = crow[e4]; float4 h = hrow[e4];
            float4 a0 = w0[e4], a1 = w1[e4], a2 = w2[e4];
            float4 b0 = u0[e4], b1 = u1[e4], b2 = u2[e4];
            ar += c.x*a0.x + c.y*a0.y + c.z*a0.z + c.w*a0.w;
            az += c.x*a1.x + c.y*a1.y + c.z*a1.z + c.w*a1.w;
            an += c.x*a2.x + c.y*a2.y + c.z*a2.z + c.w*a2.w;
            br += h.x*b0.x + h.y*b0.y + h.z*b0.z + h.w*b0.w;
            bz += h.x*b1.x + h.y*b1.y + h.z*b1.z + h.w*b1.w;
            bn += h.x*b2.x + h.y*b2.y + h.z*b2.z + h.w*b2.w;
        }
        pGI[role][b][j][0]=ar; pGI[role][b][j][1]=az; pGI[role][b][j][2]=an;
        pGH[role][b][j][0]=br; pGH[role][b][j][1]=bz; pGH[role][b][j][2]=bn;
    }
    __syncthreads();
    // gates + h_new — precise expf/tanhf: error here compounds through the
    // 256-step h recurrence, and this path is ~10^4x colder than attention.
    if (threadIdx.x < 256){
        int tok = (t == 0) ? 0 : tgt[(size_t)(bg+b)*TT + (t-1)];
        const float* er = embp + (size_t)tok*TH3 + r0;
        float gir = pGI[0][b][j][0]+pGI[1][b][j][0] + er[0];
        float giz = pGI[0][b][j][1]+pGI[1][b][j][1] + er[512];
        float gin = pGI[0][b][j][2]+pGI[1][b][j][2] + er[1024];
        float ghr = pGH[0][b][j][0]+pGH[1][b][j][0] + bhh[r0];
        float ghz = pGH[0][b][j][1]+pGH[1][b][j][1] + bhh[r0+512];
        float ghn = pGH[0][b][j][2]+pGH[1][b][j][2] + bhh[r0+1024];
        float rr = 1.f/(1.f + expf(-(gir + ghr)));
        float zz = 1.f/(1.f + expf(-(giz + ghz)));
        float nn2 = tanhf(gin + rr*ghn);
        float hv = stH[b][r0];
        float hn = (1.f - zz)*nn2 + zz*hv;
        hout[(size_t)(bg+b)*HH + r0] = hn;
        hn_l[b][j] = hn;
    }
    __syncthreads();
    // q(t+1) partial: qpart[jt][b][a] = sum_{j in tile} h_new[b, jbase+j] * Wc[jbase+j, a]
    for (int o = threadIdx.x; o < 16*AA; o += 512){
        int bb_ = o >> 8, a = o & 255;
        float acc = 0.f;
        #pragma unroll
        for (int jj = 0; jj < 16; ++jj) acc += hn_l[bb_][jj]*Wc[(size_t)(jbase+jj)*AA + a];
        qpart[((size_t)jt*BB + bg + bb_)*AA + a] = acc;
    }
}

// ---------------- epilogue ----------------
__global__ __launch_bounds__(512) void k_logits_ep(int tpred, const float* __restrict__ hsrc,
    const float* __restrict__ WfcT, const float* __restrict__ bfc, float* __restrict__ preds)
{
    __shared__ __align__(16) float hl[8*HH];
    logits_body(tpred, (int)blockIdx.x >> 3, (int)blockIdx.x & 7, hsrc, WfcT, bfc, preds, hl);
}

__global__ __launch_bounds__(512) void k_loss_ep(int tpred, const float* __restrict__ preds,
    const int* __restrict__ tgt, float* __restrict__ loss_acc)
{
    loss_body(tpred, (int)blockIdx.x, preds, tgt, loss_acc);
}

__global__ void k_final(const float* __restrict__ loss_acc, float* __restrict__ out){
    // losses.sum()/T/B where each loss_t already has 1/B  ->  / (T*B*B)
    out[0] = loss_acc[0] * (1.f/4194304.f);
}

// ---------------- host ----------------
extern "C" void kernel_launch(void* const* d_in, const int* in_sizes, int n_in,
                              void* d_out, int out_size, void* d_ws, size_t ws_size,
                              hipStream_t stream)
{
    const float* feats = (const float*)d_in[0];
    const float* shs   = (const float*)d_in[1];
    const int*   tgt   = (const int*)d_in[2];
    const float* Wf    = (const float*)d_in[3];
    const float* bf    = (const float*)d_in[4];
    const float* Ws    = (const float*)d_in[5];
    const float* bs    = (const float*)d_in[6];
    const float* Wc    = (const float*)d_in[7];
    const float* bc    = (const float*)d_in[8];
    const float* vatt  = (const float*)d_in[9];
    const float* emb   = (const float*)d_in[10];
    const float* Wih   = (const float*)d_in[11];
    const float* Whh   = (const float*)d_in[12];
    const float* bih   = (const float*)d_in[13];
    const float* bhh   = (const float*)d_in[14];
    const float* Wfc   = (const float*)d_in[15];
    const float* bfc   = (const float*)d_in[16];
    float* preds = (float*)d_out;

    char* base = (char*)d_ws;
    size_t off = 0;
    auto alloc = [&](size_t nfloats) -> float* {
        float* ptr = (float*)(base + off);
        off += ((nfloats*sizeof(float) + 255)/256)*256;
        return ptr;
    };
    float* fpT   = alloc((size_t)BNROWS*AA);   // 13.1M  feat_proj TRANSPOSED [b][a][n]
    float* embp  = alloc((size_t)VV*TH3);      // 1.54M  emb@W_ih_emb^T + b_ih
    float* wT    = alloc((size_t)EMBD*TH3);    // 0.39M
    float* wfcT  = alloc((size_t)VV*HH);       // 0.51M  W_fc transposed [v][h]
    float* sp2   = alloc((size_t)BB*AA);       // struct_proj + bs + bc
    float* qpart = alloc((size_t)32*BB*AA);    // 32 j-tile partials of h@Wc
    float* pctx  = alloc((size_t)BB*4*EE);     // unnormalized context quarters
    float* psum  = alloc((size_t)BB*4);        // exp-sum quarters
    float* hbuf  = alloc((size_t)2*BB*HH);     // double-buffered h
    float* lacc  = alloc(16);                  // loss accumulator
    (void)ws_size; (void)in_sizes; (void)n_in; (void)out_size;

    k_zero<<<(BB*HH + 511)/512, 512, 0, stream>>>(hbuf, lacc);
    k_featproj<<<dim3(BNROWS/64, AA/64), 256, 0, stream>>>(feats, Wf, bf, fpT);
    k_wembT<<<(EMBD*TH3)/256, 256, 0, stream>>>(Wih, wT);
    k_wfcT<<<(VV*HH + 255)/256, 256, 0, stream>>>(Wfc, wfcT);
    k_embproj<<<dim3(63, TH3/256), 256, 0, stream>>>(emb, wT, bih, embp);
    k_structproj<<<BB, 256, 0, stream>>>(shs, Ws, bs, bc, sp2);

    for (int t = 0; t < TT; ++t){
        const float* hin = hbuf + (size_t)(t & 1)*BB*HH;
        float*       hout = hbuf + (size_t)((t + 1) & 1)*BB*HH;
        k_attn<<<640, 512, 0, stream>>>(t, fpT, feats, sp2, vatt, qpart,
                                        hin, wfcT, bfc, pctx, psum, preds);
        k_gru<<<264, 512, 0, stream>>>(t, pctx, psum, hin, hout, Wih, Whh, bhh,
                                       embp, tgt, Wc, qpart, preds, lacc);
    }
    // logits + loss for the final step (h(256) lives in buffer 0), then finalize
    k_logits_ep<<<128, 512, 0, stream>>>(TT-1, hbuf, wfcT, bfc, preds);
    k_loss_ep<<<8, 512, 0, stream>>>(TT-1, preds, tgt, lacc);
    k_final<<<1, 1, 0, stream>>>(lacc, preds + NPRED);
}